// Round 1
// baseline (98.551 us; speedup 1.0000x reference)
//
#include <hip/hip_runtime.h>
#include <cstdint>
#include <cstddef>

namespace {

constexpr int TIL = 8;
constexpr int WID = 512;
constexpr int HEI = 512;
constexpr int NB  = 16;
constexpr int HWP = 256;               // half-strip width in pixels
constexpr int TPH = HWP / TIL;         // 32 tiles per half-strip
constexpr int LSTRIDE = 66;            // even: tiles 8B-aligned; 2-way bank alias = free (m136)
constexpr int CHP = TPH * LSTRIDE + 8; // 2120 floats/channel; +8 pad de-phases U/V banks
                                       // LDS = 3*2120*4 = 25440 B -> 6 blocks/CU

typedef float vf4 __attribute__((ext_vector_type(4)));   // nontemporal-store-compatible

// cos(t * pi/16) lookup, exact to fp32
constexpr float C16[17] = {
  1.0f, 0.9807852804032304f, 0.9238795325112867f, 0.8314696123025452f,
  0.7071067811865476f, 0.5555702330196022f, 0.3826834323650898f,
  0.1950903220161283f, 0.0f, -0.1950903220161283f, -0.3826834323650898f,
  -0.5555702330196022f, -0.7071067811865476f, -0.8314696123025452f,
  -0.9238795325112867f, -0.9807852804032304f, -1.0f
};

constexpr float cosp(int t) {         // cos(t*pi/16), any integer t
  int a = ((t % 32) + 32) % 32;
  return (a <= 16) ? C16[a] : C16[32 - a];
}

struct Tbl { float D[8][8]; float ID[8][8]; };

constexpr Tbl make_tbl() {
  Tbl t{};
  for (int k = 0; k < 8; ++k)
    for (int n = 0; n < 8; ++n) {
      t.D[k][n] = cosp((2 * n + 1) * k);          // cos(pi/8*(n+.5)*k)
      float v = cosp((2 * k + 1) * n);            // cos(pi/8*(k+.5)*n)
      if (n == 0) v -= 0.5f;
      t.ID[k][n] = v * 0.25f;                     // * sqrt(1/16)
    }
  return t;
}

constexpr Tbl TBL = make_tbl();

// zigzag keep masks: Y keeps 25, U/V keep 9 coefficients
constexpr bool keptY(int k, int l) { return (k + l <= 5) || (k + l == 6 && l <= 3); }
constexpr bool keptC(int k, int l) { return (k + l <= 2) || (k + l == 3 && k <= 2); }

// In-place 8x8: X -> ID @ (mask .* (D @ X @ D^T)) @ ID^T
// Register-lean: T rows die as Uv rows are born (peak live ~70 floats).
template <bool ISY>
__device__ __forceinline__ void tile_transform(float* __restrict__ t) {
  constexpr int KM = ISY ? 7 : 3;

  float T[KM][8];                      // T = D @ X, rows 0..KM-1
#pragma unroll
  for (int k = 0; k < KM; ++k)
#pragma unroll
    for (int m = 0; m < 8; ++m) T[k][m] = 0.0f;

#pragma unroll
  for (int n = 0; n < 8; ++n) {
    float x[8];
#pragma unroll
    for (int h = 0; h < 4; ++h) {      // 8B-aligned: tile base even, n*8 even
      const float2 v = ((const float2*)(t + n * 8))[h];
      x[2 * h] = v.x; x[2 * h + 1] = v.y;
    }
#pragma unroll
    for (int k = 0; k < KM; ++k) {
      const float d = TBL.D[k][n];
#pragma unroll
      for (int m = 0; m < 8; ++m) T[k][m] = __builtin_fmaf(d, x[m], T[k][m]);
    }
  }

  float Uv[KM][8];                     // Uv[k] = (mask_k .* (T[k] @ D^T)) @ ID^T
#pragma unroll
  for (int k = 0; k < KM; ++k) {
    float yv[8];
#pragma unroll
    for (int l = 0; l < 8; ++l) {
      if (ISY ? keptY(k, l) : keptC(k, l)) {
        float s = 0.0f;
#pragma unroll
        for (int m = 0; m < 8; ++m) s = __builtin_fmaf(T[k][m], TBL.D[l][m], s);
        yv[l] = s;
      }
    }
#pragma unroll
    for (int q = 0; q < 8; ++q) {
      float s = 0.0f;
#pragma unroll
      for (int l = 0; l < 8; ++l)
        if (ISY ? keptY(k, l) : keptC(k, l))
          s = __builtin_fmaf(yv[l], TBL.ID[q][l], s);
      Uv[k][q] = s;
    }
  }

#pragma unroll
  for (int p = 0; p < 8; ++p) {        // Z = ID(:,0:KM) @ Uv, written back
    float o[8];
#pragma unroll
    for (int q = 0; q < 8; ++q) {
      float s = 0.0f;
#pragma unroll
      for (int k = 0; k < KM; ++k) s = __builtin_fmaf(TBL.ID[p][k], Uv[k][q], s);
      o[q] = s;
    }
#pragma unroll
    for (int h = 0; h < 4; ++h)
      ((float2*)(t + p * 8))[h] = make_float2(o[2 * h], o[2 * h + 1]);
  }
}

__global__ __launch_bounds__(256) void jpeg_kernel(const float* __restrict__ in,
                                                   float* __restrict__ out) {
  __shared__ float lds[3 * CHP];       // 25440 B -> 6 blocks/CU (24 waves/CU)
  const int tid = threadIdx.x;
  const int blk = blockIdx.x;
  const int b  = blk >> 7;             // batch (128 blocks per batch)
  const int s  = (blk >> 1) & 63;      // 8-row strip index
  const int hf = blk & 1;              // left/right half of the strip
  const size_t plane = (size_t)HEI * WID;
  const size_t base0 = (size_t)b * 3 * plane + (size_t)(s * TIL) * WID
                     + (size_t)hf * HWP;

  // ---- Pass A: batch-issue all 6 float4 loads, then YUV -> LDS
  float4 rq[2], gq[2], bq[2];
  int offv[2];
#pragma unroll
  for (int it = 0; it < 2; ++it) {
    const int p4  = it * 256 + tid;    // pixel-quad 0..511 (8 rows x 64 quads)
    const int row = p4 >> 6;           // 0..7
    const int col = (p4 & 63) << 2;    // 0..252, %4==0
    const size_t g = base0 + (size_t)row * WID + col;
    rq[it] = *(const float4*)(in + g);
    gq[it] = *(const float4*)(in + g + plane);
    bq[it] = *(const float4*)(in + g + 2 * plane);
    offv[it] = (col >> 3) * LSTRIDE + row * 8 + (col & 7);   // even
  }
#pragma unroll
  for (int it = 0; it < 2; ++it) {
    const float rr[4] = {rq[it].x, rq[it].y, rq[it].z, rq[it].w};
    const float gg[4] = {gq[it].x, gq[it].y, gq[it].z, gq[it].w};
    const float bb[4] = {bq[it].x, bq[it].y, bq[it].z, bq[it].w};
    float y[4], u[4], v[4];
#pragma unroll
    for (int j = 0; j < 4; ++j) {
      const float R = rr[j], G = gg[j], Bv = bb[j];
      y[j] =  0.299f   * R + 0.587f   * G + 0.114f   * Bv;
      u[j] = -0.14713f * R - 0.28886f * G + 0.436f   * Bv;
      v[j] =  0.615f   * R - 0.51499f * G - 0.10001f * Bv;
    }
    const int off = offv[it];
    ((float2*)(lds + off))[0]           = make_float2(y[0], y[1]);
    ((float2*)(lds + off))[1]           = make_float2(y[2], y[3]);
    ((float2*)(lds + CHP + off))[0]     = make_float2(u[0], u[1]);
    ((float2*)(lds + CHP + off))[1]     = make_float2(u[2], u[3]);
    ((float2*)(lds + 2 * CHP + off))[0] = make_float2(v[0], v[1]);
    ((float2*)(lds + 2 * CHP + off))[1] = make_float2(v[2], v[3]);
  }
  __syncthreads();

  // ---- Pass B: wave0 lanes 0..31 do the 32 Y tiles (2-way banks = free);
  //      wave1 does U (lanes 0..31) and V (lanes 32..63) with a uniform code
  //      path (same template, pointer select); waves 2,3 pass through.
  if (tid < 128) {
    if (tid < 32) {
      tile_transform<true>(lds + tid * LSTRIDE);
    } else if (tid >= 64) {
      const int c = (tid >> 5) - 1;    // 64..95 -> U(1), 96..127 -> V(2)
      tile_transform<false>(lds + c * CHP + (tid & 31) * LSTRIDE);
    }
  }
  __syncthreads();

  // ---- Pass C: YUV -> RGB, coalesced nontemporal float4 stores
#pragma unroll
  for (int it = 0; it < 2; ++it) {
    const int p4  = it * 256 + tid;
    const int row = p4 >> 6;
    const int col = (p4 & 63) << 2;
    const int off = (col >> 3) * LSTRIDE + row * 8 + (col & 7);
    vf4 ro, go, bo;
#pragma unroll
    for (int h = 0; h < 2; ++h) {
      const float2 yy = ((const float2*)(lds + off))[h];
      const float2 uu = ((const float2*)(lds + CHP + off))[h];
      const float2 vv = ((const float2*)(lds + 2 * CHP + off))[h];
      ro[2 * h]     = yy.x + 1.13983f * vv.x;
      ro[2 * h + 1] = yy.y + 1.13983f * vv.y;
      go[2 * h]     = yy.x - 0.39465f * uu.x - 0.5806f * vv.x;
      go[2 * h + 1] = yy.y - 0.39465f * uu.y - 0.5806f * vv.y;
      bo[2 * h]     = yy.x + 2.03211f * uu.x;
      bo[2 * h + 1] = yy.y + 2.03211f * uu.y;
    }
    const size_t g = base0 + (size_t)row * WID + col;
    __builtin_nontemporal_store(ro, (vf4*)(out + g));
    __builtin_nontemporal_store(go, (vf4*)(out + g + plane));
    __builtin_nontemporal_store(bo, (vf4*)(out + g + 2 * plane));
  }
}

} // namespace

extern "C" void kernel_launch(void* const* d_in, const int* in_sizes, int n_in,
                              void* d_out, int out_size, void* d_ws, size_t ws_size,
                              hipStream_t stream) {
  const float* in = (const float*)d_in[0];
  float* out = (float*)d_out;
  jpeg_kernel<<<dim3(NB * (HEI / TIL) * 2), dim3(256), 0, stream>>>(in, out);
}